// Round 12
// baseline (31029.306 us; speedup 1.0000x reference)
//
#include <hip/hip_runtime.h>
#include <math.h>

#define T 16384

typedef float f32x4 __attribute__((ext_vector_type(4)));
typedef unsigned int u32x4 __attribute__((ext_vector_type(4)));
typedef _Float16 h16x2 __attribute__((ext_vector_type(2)));

__device__ __forceinline__ float softplusf_(float x) {
    return (x > 15.f) ? x : __logf(1.f + __expf(x));
}
__device__ __forceinline__ float sigmoidf_(float x) {
    return 1.f / (1.f + __expf(-x));
}
__device__ __forceinline__ float tanh_fast(float x) {
    float xc = fminf(fmaxf(x, -15.f), 15.f);
    float e = __expf(2.f * xc);
    return (e - 1.f) / (e + 1.f);
}
__device__ __forceinline__ unsigned packf16(float a, float b) {
    h16x2 p; p[0] = (_Float16)a; p[1] = (_Float16)b;   // RTN converts
    return __builtin_bit_cast(unsigned, p);
}
#define H2(u) __builtin_bit_cast(h16x2, (unsigned)(u))
// f32 += f16*f16 + f16*f16 (V_DOT2_F32_F16)
#define DOT2(ACC, UH, UW) ACC = __builtin_amdgcn_fdot2(H2(UH), H2(UW), ACC, false)

// LDS-only barrier: waits ds ops only, leaves global loads/stores in flight.
// sched_barrier(0) fences compiler motion across it (rule #18).
__device__ __forceinline__ void bar_lds() {
    asm volatile("s_waitcnt lgkmcnt(0)\n\ts_barrier" ::: "memory");
    __builtin_amdgcn_sched_barrier(0);
}

// ---------------------------------------------------------------------------
// Precompute x-dependent matvec parts + logit(eps_u) (fully parallel, f32).
// ---------------------------------------------------------------------------
__global__ __launch_bounds__(256) void k_pre(
    const float* __restrict__ x, const float* __restrict__ eu_g,
    const float* __restrict__ Wqy, const float* __restrict__ Wenc,
    const float* __restrict__ Wih,
    float* __restrict__ Aq, float* __restrict__ Ae, float* __restrict__ Ah,
    float* __restrict__ leu_g)
{
    __shared__ float xs[16 * 128];
    const int t0 = blockIdx.x * 16;
    for (int r = threadIdx.x; r < 16 * 128; r += 256) xs[r] = x[t0 * 128 + r];
    __syncthreads();
    const int j = threadIdx.x;
    if (j < 16) {
        float eu = eu_g[t0 + j];
        leu_g[t0 + j] = __logf(eu) - __logf(1.f - eu);
    }
    for (int tt = 0; tt < 16; ++tt) {
        float aq = 0.f, ae = 0.f;
#pragma unroll 8
        for (int i = 0; i < 128; ++i) {
            float xv = xs[tt * 128 + i];
            aq = fmaf(xv, Wqy[i * 256 + j], aq);
            ae = fmaf(xv, Wenc[i * 256 + j], ae);
        }
        Aq[(size_t)(t0 + tt) * 256 + j] = aq;
        Ae[(size_t)(t0 + tt) * 256 + j] = ae;
    }
    if (j < 128) {
        for (int tt = 0; tt < 16; ++tt) {
            float ah = 0.f;
#pragma unroll 8
            for (int i = 0; i < 128; ++i)
                ah = fmaf(xs[tt * 128 + i], Wih[(65 + i) * 128 + j], ah);
            Ah[(size_t)(t0 + tt) * 128 + j] = ah;
        }
    }
}

// ---------------------------------------------------------------------------
// Sequential scan: 1 block x 512 threads. f16-packed weights (r11 placement):
//   LDS : W_q_y-h (64 KB) + W_em/es (64 KB), thread-major u32x4, private slots
//   regs: W_enc-h 32 + W_hh 16 + W_ih-z 8 u32
// In-step barriers are LDS-only (global prefetch/stores stay in flight);
// full __syncthreads only at the 4-step batch boundary.
// ---------------------------------------------------------------------------
__global__
__attribute__((amdgpu_flat_work_group_size(512, 512)))
__attribute__((amdgpu_waves_per_eu(2, 2)))
void k_scan(
    const float* __restrict__ Wqy, const float* __restrict__ qpr,
    const float* __restrict__ Wenc,
    const float* __restrict__ Wem0, const float* __restrict__ Wes0,
    const float* __restrict__ Wih, const float* __restrict__ Whh,
    const float* __restrict__ yin_g, const float* __restrict__ leu_g,
    const float* __restrict__ ez_g,
    const float* __restrict__ Aq, const float* __restrict__ Ae,
    const float* __restrict__ Ah,
    float* __restrict__ h_st, float* __restrict__ z_st,
    float* __restrict__ em_st, float* __restrict__ es_st,
    float* __restrict__ y_st)
{
    const int tid = threadIdx.x;
    const int j   = tid >> 1, c1 = tid & 1;                          // S1/S3
    const int m4  = tid >> 3; const int k4s = (tid >> 2) & 1; const int c4 = tid & 3; // S4
    const int o5  = tid >> 2, c5 = tid & 3;                          // S5

    // ---- LDS (~145 KB) ----
    __shared__ __align__(16) u32x4 wq2[8][512];      // 64 KB W_q_y h-part (f16)
    __shared__ __align__(16) u32x4 wm2[8][512];      // 64 KB W_em/es (f16)
    __shared__ __align__(16) float s_aq[4][256];
    __shared__ __align__(16) float s_ae[4][256];
    __shared__ __align__(16) float s_ah[4][128];
    __shared__ __align__(16) float s_ez[4][64];
    __shared__ __align__(16) float s_yin[4];
    __shared__ __align__(16) float s_leu[4];
    __shared__ __align__(16) float t_h[4][128];
    __shared__ __align__(16) float t_z[4][64];
    __shared__ __align__(16) float t_em[4][64];
    __shared__ __align__(16) float t_es[4][64];
    __shared__ float t_y[4];
    __shared__ __align__(16) unsigned hh2[2][64];    // h packed (f16 pairs)
    __shared__ __align__(16) unsigned eh2[128];      // eh packed
    __shared__ __align__(16) unsigned z2[32];        // z packed
    __shared__ float red[8];

    // ---- register weights (f16-packed u32, constant indices) ----
    unsigned weh2_[32];                              // W_enc-h chunk (64 f)
#pragma unroll
    for (int g = 0; g < 8; ++g)
#pragma unroll
        for (int e = 0; e < 4; ++e) {
            const int k = g * 8 + 2 * e;
            weh2_[g * 4 + e] = packf16(Wenc[(129 + c1 * 64 + k) * 256 + j],
                                       Wenc[(129 + c1 * 64 + k + 1) * 256 + j]);
        }
    unsigned wh2_[16];                               // W_hh chunk (32 f)
#pragma unroll
    for (int g = 0; g < 4; ++g)
#pragma unroll
        for (int e = 0; e < 4; ++e) {
            const int k = g * 8 + 2 * e;
            wh2_[g * 4 + e] = packf16(Whh[(c5 * 32 + k) * 128 + o5],
                                      Whh[(c5 * 32 + k + 1) * 128 + o5]);
        }
    unsigned wz2_[8];                                // W_ih-z chunk (16 f)
#pragma unroll
    for (int p = 0; p < 8; ++p)
        wz2_[p] = packf16(Wih[(1 + c5 * 16 + 2 * p) * 128 + o5],
                          Wih[(1 + c5 * 16 + 2 * p + 1) * 128 + o5]);
    const float wey  = Wenc[128 * 256 + j];
    const float qpj  = qpr[j];
    const float wihy = Wih[o5];

    // ---- LDS weights: W_q_y h-part + W_em/es, thread-major ----
    for (int g = 0; g < 8; ++g) {
        u32x4 v;
#pragma unroll
        for (int e = 0; e < 4; ++e) {
            const int k = g * 8 + 2 * e;
            v[e] = packf16(Wqy[(128 + c1 * 64 + k) * 256 + j],
                           Wqy[(128 + c1 * 64 + k + 1) * 256 + j]);
        }
        wq2[g][tid] = v;
    }
    {
        const float* Wm = k4s ? Wes0 : Wem0;
        for (int g = 0; g < 8; ++g) {
            u32x4 v;
#pragma unroll
            for (int e = 0; e < 4; ++e) {
                const int k = g * 8 + 2 * e;
                v[e] = packf16(Wm[(c4 * 64 + k) * 64 + m4],
                               Wm[(c4 * 64 + k + 1) * 64 + m4]);
            }
            wm2[g][tid] = v;
        }
    }
    if (tid < 64) hh2[0][tid] = 0u;                  // h(0) = 0

    // ---- staging: global -> regs (early) -> LDS (late) ----
    f32x4 pA, pC;
    auto load_regs = [&](int t0) {
        if (tid < 256) pA = ((const f32x4*)(Aq + (size_t)t0 * 256))[tid];
        else           pA = ((const f32x4*)(Ae + (size_t)t0 * 256))[tid - 256];
        if (tid < 128)       pC = ((const f32x4*)(Ah + (size_t)t0 * 128))[tid];
        else if (tid < 192)  pC = ((const f32x4*)(ez_g + (size_t)t0 * 64))[tid - 128];
        else if (tid == 192) pC = *(const f32x4*)(yin_g + t0);
        else if (tid == 193) pC = *(const f32x4*)(leu_g + t0);
    };
    auto write_regs = [&]() {
        if (tid < 256) ((f32x4*)&s_aq[0][0])[tid] = pA;
        else           ((f32x4*)&s_ae[0][0])[tid - 256] = pA;
        if (tid < 128)       ((f32x4*)&s_ah[0][0])[tid] = pC;
        else if (tid < 192)  ((f32x4*)&s_ez[0][0])[tid - 128] = pC;
        else if (tid == 192) *(f32x4*)s_yin = pC;
        else if (tid == 193) *(f32x4*)s_leu = pC;
    };
    auto flushb = [&](int t0) {
        if (tid < 128) {
            ((f32x4*)(h_st + (size_t)t0 * 128))[tid] = ((const f32x4*)&t_h[0][0])[tid];
        } else if (tid < 192) {
            ((f32x4*)(z_st + (size_t)t0 * 64))[tid - 128] = ((const f32x4*)&t_z[0][0])[tid - 128];
        } else if (tid < 256) {
            ((f32x4*)(em_st + (size_t)t0 * 64))[tid - 192] = ((const f32x4*)&t_em[0][0])[tid - 192];
        } else if (tid < 320) {
            ((f32x4*)(es_st + (size_t)t0 * 64))[tid - 256] = ((const f32x4*)&t_es[0][0])[tid - 256];
        } else if (tid < 324) {
            y_st[t0 + (tid - 320)] = t_y[tid - 320];
        }
    };

    load_regs(0);
    write_regs();
    __syncthreads();

    for (int t0 = 0; t0 < T; t0 += 4) {
        const int tnb = (t0 + 4 < T) ? t0 + 4 : t0;
        load_regs(tnb);                                    // issue early (T14)

        for (int tt = 0; tt < 4; ++tt) {
            const int t = t0 + tt;
            const int cur = t & 1, nxt = cur ^ 1;
            const float aq  = s_aq[tt][j];
            const float ae  = s_ae[tt][j];
            const float yin = s_yin[tt];
            const float leu = s_leu[tt];
            const float ezv = s_ez[tt][m4];
            const float ahv = s_ah[tt][o5];
            const u32x4* __restrict__ hh4 = (const u32x4*)&hh2[cur][0];

            float y_t, ehdot;
            if (yin == -1.0f) {
                // fused q-dot (LDS f16) + eh-dot (reg f16), shared h pairs
                float a0 = 0.f, a1 = 0.f, e0 = 0.f, e1 = 0.f;
#pragma unroll
                for (int g = 0; g < 8; ++g) {
                    u32x4 hv = hh4[c1 * 8 + g];
                    u32x4 qv = wq2[g][tid];
                    DOT2(a0, hv[0], qv[0]); DOT2(a1, hv[1], qv[1]);
                    DOT2(a0, hv[2], qv[2]); DOT2(a1, hv[3], qv[3]);
                    DOT2(e0, hv[0], weh2_[g * 4 + 0]);
                    DOT2(e1, hv[1], weh2_[g * 4 + 1]);
                    DOT2(e0, hv[2], weh2_[g * 4 + 2]);
                    DOT2(e1, hv[3], weh2_[g * 4 + 3]);
                }
                float s = a0 + a1;
                ehdot   = e0 + e1;
                s += __shfl_xor(s, 1);
                ehdot += __shfl_xor(ehdot, 1);
                float qh = fmaxf(aq + s, 0.f);
                float cq = (c1 == 0) ? qh * qpj : 0.f;
#pragma unroll
                for (int d = 1; d < 64; d <<= 1) cq += __shfl_xor(cq, d);
                if ((tid & 63) == 0) red[tid >> 6] = cq;
                bar_lds();                                 // B1 (LDS-only)
                float qlog = ((red[0] + red[1]) + (red[2] + red[3])) +
                             ((red[4] + red[5]) + (red[6] + red[7]));
                y_t = sigmoidf_(leu + qlog);
            } else {
                float e0 = 0.f, e1 = 0.f;
#pragma unroll
                for (int g = 0; g < 8; ++g) {
                    u32x4 hv = hh4[c1 * 8 + g];
                    DOT2(e0, hv[0], weh2_[g * 4 + 0]);
                    DOT2(e1, hv[1], weh2_[g * 4 + 1]);
                    DOT2(e0, hv[2], weh2_[g * 4 + 2]);
                    DOT2(e1, hv[3], weh2_[g * 4 + 3]);
                }
                ehdot = e0 + e1;
                ehdot += __shfl_xor(ehdot, 1);
                y_t = yin;
            }

            // S3 finalize: eh = relu(Ae + y*wey + h-dot); pack pairs
            {
                float eh = fmaxf(fmaf(y_t, wey, ae) + ehdot, 0.f);
                float epart = __shfl_xor(eh, 2);           // j^1 partner
                if ((tid & 3) == 0) eh2[j >> 1] = packf16(eh, epart);
            }
            bar_lds();                                     // B3 (LDS-only)

            // S4: em/es over eh(256); z = ez*softplus(es)+em
            {
                const u32x4* __restrict__ eb4 = (const u32x4*)eh2;
                float b0 = 0.f, b1 = 0.f;
#pragma unroll
                for (int g = 0; g < 8; ++g) {
                    u32x4 ev = eb4[c4 * 8 + g];
                    u32x4 wv = wm2[g][tid];
                    DOT2(b0, ev[0], wv[0]); DOT2(b1, ev[1], wv[1]);
                    DOT2(b0, ev[2], wv[2]); DOT2(b1, ev[3], wv[3]);
                }
                float s = b0 + b1;
                s += __shfl_xor(s, 1);
                s += __shfl_xor(s, 2);
                float other = __shfl_xor(s, 4);
                float em_pre = k4s ? other : s;
                float es_pre = k4s ? s : other;
                float es = softplusf_(es_pre);
                float zm = fmaf(ezv, es, em_pre);
                float zpart = __shfl_xor(zm, 8);           // m4^1 partner
                if ((tid & 7) == 0) {
                    t_z[tt][m4] = zm; t_em[tt][m4] = em_pre; t_es[tt][m4] = es;
                }
                if ((tid & 15) == 0) z2[m4 >> 1] = packf16(zm, zpart);
            }
            bar_lds();                                     // B4 (LDS-only)

            // S5: h' = tanh(Ah + y*wihy + z@Wih_z + h@W_hh); pack pairs
            {
                const u32x4* __restrict__ zb4 = (const u32x4*)z2;
                float g0 = 0.f, g1 = 0.f;
#pragma unroll
                for (int g = 0; g < 2; ++g) {
                    u32x4 zv = zb4[c5 * 2 + g];
                    DOT2(g0, zv[0], wz2_[g * 4 + 0]);
                    DOT2(g1, zv[1], wz2_[g * 4 + 1]);
                    DOT2(g0, zv[2], wz2_[g * 4 + 2]);
                    DOT2(g1, zv[3], wz2_[g * 4 + 3]);
                }
#pragma unroll
                for (int g = 0; g < 4; ++g) {
                    u32x4 hv = hh4[c5 * 4 + g];
                    DOT2(g0, hv[0], wh2_[g * 4 + 0]);
                    DOT2(g1, hv[1], wh2_[g * 4 + 1]);
                    DOT2(g0, hv[2], wh2_[g * 4 + 2]);
                    DOT2(g1, hv[3], wh2_[g * 4 + 3]);
                }
                float s = g0 + g1;
                s += __shfl_xor(s, 1);
                s += __shfl_xor(s, 2);
                float hn = tanh_fast(fmaf(y_t, wihy, ahv) + s);
                float hpart = __shfl_xor(hn, 4);           // o5^1 partner
                if (c5 == 0) t_h[tt][o5] = hn;
                if ((tid & 7) == 0) hh2[nxt][o5 >> 1] = packf16(hn, hpart);
                if (tid == 0) t_y[tt] = y_t;
            }
            bar_lds();                                     // B5 (LDS-only)
        }

        flushb(t0);            // trajectory for this batch (fire-and-forget)
        write_regs();          // s_* for next batch (waits pA/pC via vmcnt)
        __syncthreads();       // batch barrier (full drain, once per 4 steps)
    }
}

// ---------------------------------------------------------------------------
// Post-pass: one block per timestep (unchanged, full f32).
// ---------------------------------------------------------------------------
__global__ __launch_bounds__(256) void k_post(
    const float* __restrict__ x, const float* __restrict__ yin_g,
    const float* __restrict__ Wpz, const float* __restrict__ Wpzm,
    const float* __restrict__ Wpzs,
    const float* __restrict__ Wpy, const float* __restrict__ ppr,
    const float* __restrict__ Wqy, const float* __restrict__ qpr,
    const float* __restrict__ Wd, const float* __restrict__ Wdm,
    const float* __restrict__ Wds,
    const float* __restrict__ Aq,
    const float* __restrict__ h_st, const float* __restrict__ z_st,
    const float* __restrict__ em_st, const float* __restrict__ es_st,
    const float* __restrict__ y_st,
    float* __restrict__ part)
{
    const float CC = -0.9189385332046727f;  // -0.5*log(2*pi)
    const int t = blockIdx.x;
    const int tid = threadIdx.x;
    __shared__ float xp[128], xdv[128], xcv[128], hp[128];
    __shared__ float zp[64], ztv[64], emv[64], esv[64];
    __shared__ float pzh[256], dhv[256];
    __shared__ float pmv[64], psv[64], dmv[128], dsv[128];
    __shared__ float rl[16];

    const int tp = t ? (t - 1) : (T - 1);
    if (tid < 128) {
        xp[tid]  = x[(size_t)tp * 128 + tid];
        xdv[tid] = t ? x[(size_t)(t - 1) * 128 + tid] : 0.f;
        xcv[tid] = x[(size_t)t * 128 + tid];
        hp[tid]  = t ? h_st[(size_t)(t - 1) * 128 + tid] : 0.f;
    } else {
        int m = tid - 128;
        if (m < 64) {
            zp[m]  = t ? z_st[(size_t)(t - 1) * 64 + m] : 0.f;
            ztv[m] = z_st[(size_t)t * 64 + m];
        } else {
            m -= 64;
            emv[m] = em_st[(size_t)t * 64 + m];
            esv[m] = es_st[(size_t)t * 64 + m];
        }
    }
    __syncthreads();

    const float y_t = y_st[t];
    const float y_prev = t ? y_st[t - 1] : 0.f;
    const float lf = (yin_g[t] != -1.0f) ? 1.f : 0.f;
    const int jj = tid;

    float ap = 0.f;
#pragma unroll 4
    for (int i = 0; i < 128; ++i) ap = fmaf(xp[i], Wpy[i * 256 + jj], ap);
    ap = fmaf(y_prev, Wpy[128 * 256 + jj], ap);
    float cp = fmaxf(ap, 0.f) * ppr[jj];

    float aqv = Aq[(size_t)t * 256 + jj];
#pragma unroll 4
    for (int i = 0; i < 128; ++i) aqv = fmaf(hp[i], Wqy[(128 + i) * 256 + jj], aqv);
    float cq = fmaxf(aqv, 0.f) * qpr[jj];

    float az = 0.f;
#pragma unroll 4
    for (int m = 0; m < 64; ++m) az = fmaf(zp[m], Wpz[m * 256 + jj], az);
    pzh[jj] = fmaxf(az, 0.f);

    float ad = 0.f;
#pragma unroll 4
    for (int i = 0; i < 128; ++i) ad = fmaf(xdv[i], Wd[i * 256 + jj], ad);
#pragma unroll 4
    for (int m = 0; m < 64; ++m) ad = fmaf(ztv[m], Wd[(128 + m) * 256 + jj], ad);
    ad = fmaf(y_t, Wd[192 * 256 + jj], ad);
    dhv[jj] = fmaxf(ad, 0.f);
    __syncthreads();

    {
        const int i_ = tid & 127;
        const float* W = (tid < 128) ? Wdm : Wds;
        float a = 0.f;
#pragma unroll 4
        for (int q2 = 0; q2 < 256; ++q2) a = fmaf(dhv[q2], W[q2 * 128 + i_], a);
        if (tid < 128) dmv[i_] = a; else dsv[i_] = softplusf_(a);
    }
    if (tid < 128) {
        const int m = tid & 63;
        const float* W = (tid < 64) ? Wpzm : Wpzs;
        float a = 0.f;
#pragma unroll 4
        for (int q2 = 0; q2 < 256; ++q2) a = fmaf(pzh[q2], W[q2 * 64 + m], a);
        if (tid < 64) pmv[m] = a; else psv[m] = softplusf_(a);
    }
    __syncthreads();

    float kldc = 0.f, recc = 0.f;
    if (tid < 64) {
        float es = esv[tid], em = emv[tid], pm = pmv[tid], ps = psv[tid];
        float d = em - pm;
        kldc = __logf(ps / es) + (es * es + d * d) / (2.f * ps * ps) - 0.5f;
    }
    if (tid < 128) {
        float dm = dmv[tid], ds = dsv[tid], xv = xcv[tid];
        float d = xv - dm;
        recc = CC + __logf(ds) + d * d / (2.f * ds * ds);
    }

#pragma unroll
    for (int d = 1; d < 64; d <<= 1) {
        cp += __shfl_xor(cp, d);
        cq += __shfl_xor(cq, d);
        kldc += __shfl_xor(kldc, d);
        recc += __shfl_xor(recc, d);
    }
    if ((tid & 63) == 0) {
        const int w = tid >> 6;
        rl[w * 4 + 0] = cp; rl[w * 4 + 1] = cq;
        rl[w * 4 + 2] = kldc; rl[w * 4 + 3] = recc;
    }
    __syncthreads();
    if (tid == 0) {
        float plog = rl[0] + rl[4] + rl[8]  + rl[12];
        float qlog = rl[1] + rl[5] + rl[9]  + rl[13];
        float kld  = rl[2] + rl[6] + rl[10] + rl[14];
        float rec  = rl[3] + rl[7] + rl[11] + rl[15];
        float p = sigmoidf_(plog), q = sigmoidf_(qlog);
        float bce  = -(y_t * __logf(p) + (1.f - y_t) * __logf(1.f - p));
        float addt = y_t * __logf(p * q) + (1.f - y_t) * __logf((1.f - p) * (1.f - q));
        float kcat = p * __logf(p / q) + (1.f - p) * __logf((1.f - p) / (1.f - q));
        float ul = 1.f - lf;
        float* pr = part + (size_t)t * 7;
        pr[0] = lf * kld;  pr[1] = lf * rec;  pr[2] = lf * bce;
        pr[3] = ul * kld;  pr[4] = ul * rec;  pr[5] = ul * kcat;
        pr[6] = lf * addt;
    }
}

__global__ __launch_bounds__(256) void k_final(const float* __restrict__ part,
                                               float* __restrict__ out)
{
    const int o = blockIdx.x;
    float s = 0.f;
    for (int b = threadIdx.x; b < T; b += 256) s += part[(size_t)b * 7 + o];
#pragma unroll
    for (int d = 1; d < 64; d <<= 1) s += __shfl_xor(s, d);
    __shared__ float l[4];
    if ((threadIdx.x & 63) == 0) l[threadIdx.x >> 6] = s;
    __syncthreads();
    if (threadIdx.x == 0) out[o] = (l[0] + l[1]) + (l[2] + l[3]);
}

extern "C" void kernel_launch(void* const* d_in, const int* in_sizes, int n_in,
                              void* d_out, int out_size, void* d_ws, size_t ws_size,
                              hipStream_t stream) {
    (void)in_sizes; (void)n_in; (void)out_size; (void)ws_size;
    const float* x    = (const float*)d_in[0];
    const float* yin  = (const float*)d_in[1];
    const float* ez   = (const float*)d_in[2];
    const float* eu   = (const float*)d_in[3];
    const float* Wpz  = (const float*)d_in[4];
    const float* Wpzm = (const float*)d_in[5];
    const float* Wpzs = (const float*)d_in[6];
    const float* Wpy  = (const float*)d_in[7];
    const float* ppr  = (const float*)d_in[8];
    const float* Wqy  = (const float*)d_in[9];
    const float* qpr  = (const float*)d_in[10];
    const float* Wenc = (const float*)d_in[11];
    const float* Wem  = (const float*)d_in[12];
    const float* Wes  = (const float*)d_in[13];
    const float* Wd   = (const float*)d_in[14];
    const float* Wdm  = (const float*)d_in[15];
    const float* Wds  = (const float*)d_in[16];
    const float* Wih  = (const float*)d_in[17];
    const float* Whh  = (const float*)d_in[18];

    float* ws = (float*)d_ws;
    float* Aq    = ws;                           // T*256
    float* Ae    = Aq    + (size_t)T * 256;      // T*256
    float* Ah    = Ae    + (size_t)T * 256;      // T*128
    float* h_st  = Ah    + (size_t)T * 128;      // T*128
    float* z_st  = h_st  + (size_t)T * 128;      // T*64
    float* em_st = z_st  + (size_t)T * 64;       // T*64
    float* es_st = em_st + (size_t)T * 64;       // T*64
    float* y_st  = es_st + (size_t)T * 64;       // T
    float* part  = y_st  + (size_t)T;            // T*7
    float* leu   = part  + (size_t)T * 7;        // T

    k_pre<<<T / 16, 256, 0, stream>>>(x, eu, Wqy, Wenc, Wih, Aq, Ae, Ah, leu);
    k_scan<<<1, 512, 0, stream>>>(Wqy, qpr, Wenc, Wem, Wes, Wih, Whh,
                                  yin, leu, ez, Aq, Ae, Ah,
                                  h_st, z_st, em_st, es_st, y_st);
    k_post<<<T, 256, 0, stream>>>(x, yin, Wpz, Wpzm, Wpzs, Wpy, ppr, Wqy, qpr,
                                  Wd, Wdm, Wds, Aq, h_st, z_st, em_st, es_st,
                                  y_st, part);
    k_final<<<7, 256, 0, stream>>>(part, (float*)d_out);
}

// Round 14
// 25961.673 us; speedup vs baseline: 1.1952x; 1.1952x over previous
//
#include <hip/hip_runtime.h>
#include <math.h>

#define T 16384

typedef float f32x4 __attribute__((ext_vector_type(4)));
typedef unsigned int u32x4 __attribute__((ext_vector_type(4)));
typedef _Float16 h16x2 __attribute__((ext_vector_type(2)));

__device__ __forceinline__ float softplusf_(float x) {
    return (x > 15.f) ? x : __logf(1.f + __expf(x));
}
__device__ __forceinline__ float sigmoidf_(float x) {
    return 1.f / (1.f + __expf(-x));
}
__device__ __forceinline__ float tanh_fast(float x) {
    float xc = fminf(fmaxf(x, -15.f), 15.f);
    float e = __expf(2.f * xc);
    return (e - 1.f) / (e + 1.f);
}
__device__ __forceinline__ unsigned packf16(float a, float b) {
    h16x2 p; p[0] = (_Float16)a; p[1] = (_Float16)b;   // RTN converts
    return __builtin_bit_cast(unsigned, p);
}
#define H2(u) __builtin_bit_cast(h16x2, (unsigned)(u))
// f32 += f16*f16 + f16*f16 (V_DOT2_F32_F16)
#define DOT2(ACC, UH, UW) ACC = __builtin_amdgcn_fdot2(H2(UH), H2(UW), ACC, false)

// ---- DPP cross-lane (VALU pipe, replaces ds_swizzle-based __shfl_xor) ----
// ctrl must be an ICE -> template parameter.
#define DPP_QX1 0xB1   // quad_perm(1,0,3,2)  == xor 1
#define DPP_QX2 0x4E   // quad_perm(2,3,0,1)  == xor 2
#define DPP_RHM 0x141  // row_half_mirror (7-i in 8)  == xor 4 on quad-uniform
#define DPP_RM  0x140  // row_mirror (15-i in 16)     == xor 8 on 8-uniform
#define DPP_B15 0x142  // row_bcast15
#define DPP_B31 0x143  // row_bcast31
template <int CTRL>
__device__ __forceinline__ float dpp_mov(float s) {
    return __builtin_bit_cast(float,
        __builtin_amdgcn_update_dpp(0, __builtin_bit_cast(int, s), CTRL, 0xf, 0xf, true));
}
template <int CTRL>
__device__ __forceinline__ float dpp_add(float s) {
    return s + dpp_mov<CTRL>(s);
}

// ---------------------------------------------------------------------------
// Precompute x-dependent matvec parts + logit(eps_u) (fully parallel, f32).
// ---------------------------------------------------------------------------
__global__ __launch_bounds__(256) void k_pre(
    const float* __restrict__ x, const float* __restrict__ eu_g,
    const float* __restrict__ Wqy, const float* __restrict__ Wenc,
    const float* __restrict__ Wih,
    float* __restrict__ Aq, float* __restrict__ Ae, float* __restrict__ Ah,
    float* __restrict__ leu_g)
{
    __shared__ float xs[16 * 128];
    const int t0 = blockIdx.x * 16;
    for (int r = threadIdx.x; r < 16 * 128; r += 256) xs[r] = x[t0 * 128 + r];
    __syncthreads();
    const int j = threadIdx.x;
    if (j < 16) {
        float eu = eu_g[t0 + j];
        leu_g[t0 + j] = __logf(eu) - __logf(1.f - eu);
    }
    for (int tt = 0; tt < 16; ++tt) {
        float aq = 0.f, ae = 0.f;
#pragma unroll 8
        for (int i = 0; i < 128; ++i) {
            float xv = xs[tt * 128 + i];
            aq = fmaf(xv, Wqy[i * 256 + j], aq);
            ae = fmaf(xv, Wenc[i * 256 + j], ae);
        }
        Aq[(size_t)(t0 + tt) * 256 + j] = aq;
        Ae[(size_t)(t0 + tt) * 256 + j] = ae;
    }
    if (j < 128) {
        for (int tt = 0; tt < 16; ++tt) {
            float ah = 0.f;
#pragma unroll 8
            for (int i = 0; i < 128; ++i)
                ah = fmaf(xs[tt * 128 + i], Wih[(65 + i) * 128 + j], ah);
            Ah[(size_t)(t0 + tt) * 128 + j] = ah;
        }
    }
}

// ---------------------------------------------------------------------------
// Sequential scan: 1 block x 512 threads. f16-packed weights (r11 placement):
//   LDS : W_q_y-h (64 KB) + W_em/es (64 KB), thread-major u32x4, private slots
//   regs: W_enc-h 32 + W_hh 16 + W_ih-z 8 u32
// Cross-lane ops via DPP (VALU) instead of __shfl_xor (ds_swizzle, ~120cy).
// Barrier structure identical to r11 (plain __syncthreads).
// ---------------------------------------------------------------------------
__global__
__attribute__((amdgpu_flat_work_group_size(512, 512)))
__attribute__((amdgpu_waves_per_eu(2, 2)))
void k_scan(
    const float* __restrict__ Wqy, const float* __restrict__ qpr,
    const float* __restrict__ Wenc,
    const float* __restrict__ Wem0, const float* __restrict__ Wes0,
    const float* __restrict__ Wih, const float* __restrict__ Whh,
    const float* __restrict__ yin_g, const float* __restrict__ leu_g,
    const float* __restrict__ ez_g,
    const float* __restrict__ Aq, const float* __restrict__ Ae,
    const float* __restrict__ Ah,
    float* __restrict__ h_st, float* __restrict__ z_st,
    float* __restrict__ em_st, float* __restrict__ es_st,
    float* __restrict__ y_st)
{
    const int tid = threadIdx.x;
    const int j   = tid >> 1, c1 = tid & 1;                          // S1/S3
    const int m4  = tid >> 3; const int k4s = (tid >> 2) & 1; const int c4 = tid & 3; // S4
    const int o5  = tid >> 2, c5 = tid & 3;                          // S5

    // ---- LDS (~145 KB) ----
    __shared__ __align__(16) u32x4 wq2[8][512];      // 64 KB W_q_y h-part (f16)
    __shared__ __align__(16) u32x4 wm2[8][512];      // 64 KB W_em/es (f16)
    __shared__ __align__(16) float s_aq[4][256];
    __shared__ __align__(16) float s_ae[4][256];
    __shared__ __align__(16) float s_ah[4][128];
    __shared__ __align__(16) float s_ez[4][64];
    __shared__ __align__(16) float s_yin[4];
    __shared__ __align__(16) float s_leu[4];
    __shared__ __align__(16) float t_h[4][128];
    __shared__ __align__(16) float t_z[4][64];
    __shared__ __align__(16) float t_em[4][64];
    __shared__ __align__(16) float t_es[4][64];
    __shared__ float t_y[4];
    __shared__ __align__(16) unsigned hh2[2][64];    // h packed (f16 pairs)
    __shared__ __align__(16) unsigned eh2[128];      // eh packed
    __shared__ __align__(16) unsigned z2[32];        // z packed
    __shared__ float red[8];

    // ---- register weights (f16-packed u32, constant indices) ----
    unsigned weh2_[32];                              // W_enc-h chunk (64 f)
#pragma unroll
    for (int g = 0; g < 8; ++g)
#pragma unroll
        for (int e = 0; e < 4; ++e) {
            const int k = g * 8 + 2 * e;
            weh2_[g * 4 + e] = packf16(Wenc[(129 + c1 * 64 + k) * 256 + j],
                                       Wenc[(129 + c1 * 64 + k + 1) * 256 + j]);
        }
    unsigned wh2_[16];                               // W_hh chunk (32 f)
#pragma unroll
    for (int g = 0; g < 4; ++g)
#pragma unroll
        for (int e = 0; e < 4; ++e) {
            const int k = g * 8 + 2 * e;
            wh2_[g * 4 + e] = packf16(Whh[(c5 * 32 + k) * 128 + o5],
                                      Whh[(c5 * 32 + k + 1) * 128 + o5]);
        }
    unsigned wz2_[8];                                // W_ih-z chunk (16 f)
#pragma unroll
    for (int p = 0; p < 8; ++p)
        wz2_[p] = packf16(Wih[(1 + c5 * 16 + 2 * p) * 128 + o5],
                          Wih[(1 + c5 * 16 + 2 * p + 1) * 128 + o5]);
    const float wey  = Wenc[128 * 256 + j];
    const float qpj  = qpr[j];
    const float wihy = Wih[o5];

    // ---- LDS weights: W_q_y h-part + W_em/es, thread-major ----
    for (int g = 0; g < 8; ++g) {
        u32x4 v;
#pragma unroll
        for (int e = 0; e < 4; ++e) {
            const int k = g * 8 + 2 * e;
            v[e] = packf16(Wqy[(128 + c1 * 64 + k) * 256 + j],
                           Wqy[(128 + c1 * 64 + k + 1) * 256 + j]);
        }
        wq2[g][tid] = v;
    }
    {
        const float* Wm = k4s ? Wes0 : Wem0;
        for (int g = 0; g < 8; ++g) {
            u32x4 v;
#pragma unroll
            for (int e = 0; e < 4; ++e) {
                const int k = g * 8 + 2 * e;
                v[e] = packf16(Wm[(c4 * 64 + k) * 64 + m4],
                               Wm[(c4 * 64 + k + 1) * 64 + m4]);
            }
            wm2[g][tid] = v;
        }
    }
    if (tid < 64) hh2[0][tid] = 0u;                  // h(0) = 0

    // ---- staging: global -> regs (early) -> LDS (late) ----
    f32x4 pA, pC;
    auto load_regs = [&](int t0) {
        if (tid < 256) pA = ((const f32x4*)(Aq + (size_t)t0 * 256))[tid];
        else           pA = ((const f32x4*)(Ae + (size_t)t0 * 256))[tid - 256];
        if (tid < 128)       pC = ((const f32x4*)(Ah + (size_t)t0 * 128))[tid];
        else if (tid < 192)  pC = ((const f32x4*)(ez_g + (size_t)t0 * 64))[tid - 128];
        else if (tid == 192) pC = *(const f32x4*)(yin_g + t0);
        else if (tid == 193) pC = *(const f32x4*)(leu_g + t0);
    };
    auto write_regs = [&]() {
        if (tid < 256) ((f32x4*)&s_aq[0][0])[tid] = pA;
        else           ((f32x4*)&s_ae[0][0])[tid - 256] = pA;
        if (tid < 128)       ((f32x4*)&s_ah[0][0])[tid] = pC;
        else if (tid < 192)  ((f32x4*)&s_ez[0][0])[tid - 128] = pC;
        else if (tid == 192) *(f32x4*)s_yin = pC;
        else if (tid == 193) *(f32x4*)s_leu = pC;
    };
    auto flushb = [&](int t0) {
        if (tid < 128) {
            ((f32x4*)(h_st + (size_t)t0 * 128))[tid] = ((const f32x4*)&t_h[0][0])[tid];
        } else if (tid < 192) {
            ((f32x4*)(z_st + (size_t)t0 * 64))[tid - 128] = ((const f32x4*)&t_z[0][0])[tid - 128];
        } else if (tid < 256) {
            ((f32x4*)(em_st + (size_t)t0 * 64))[tid - 192] = ((const f32x4*)&t_em[0][0])[tid - 192];
        } else if (tid < 320) {
            ((f32x4*)(es_st + (size_t)t0 * 64))[tid - 256] = ((const f32x4*)&t_es[0][0])[tid - 256];
        } else if (tid < 324) {
            y_st[t0 + (tid - 320)] = t_y[tid - 320];
        }
    };

    load_regs(0);
    write_regs();
    __syncthreads();

    for (int t0 = 0; t0 < T; t0 += 4) {
        const int tnb = (t0 + 4 < T) ? t0 + 4 : t0;
        load_regs(tnb);                                    // issue early (T14)

        for (int tt = 0; tt < 4; ++tt) {
            const int t = t0 + tt;
            const int cur = t & 1, nxt = cur ^ 1;
            const float aq  = s_aq[tt][j];
            const float ae  = s_ae[tt][j];
            const float yin = s_yin[tt];
            const float leu = s_leu[tt];
            const float ezv = s_ez[tt][m4];
            const float ahv = s_ah[tt][o5];
            const u32x4* __restrict__ hh4 = (const u32x4*)&hh2[cur][0];

            float y_t, ehdot;
            if (yin == -1.0f) {
                // fused q-dot (LDS f16) + eh-dot (reg f16), shared h pairs
                float a0 = 0.f, a1 = 0.f, e0 = 0.f, e1 = 0.f;
#pragma unroll
                for (int g = 0; g < 8; ++g) {
                    u32x4 hv = hh4[c1 * 8 + g];
                    u32x4 qv = wq2[g][tid];
                    DOT2(a0, hv[0], qv[0]); DOT2(a1, hv[1], qv[1]);
                    DOT2(a0, hv[2], qv[2]); DOT2(a1, hv[3], qv[3]);
                    DOT2(e0, hv[0], weh2_[g * 4 + 0]);
                    DOT2(e1, hv[1], weh2_[g * 4 + 1]);
                    DOT2(e0, hv[2], weh2_[g * 4 + 2]);
                    DOT2(e1, hv[3], weh2_[g * 4 + 3]);
                }
                float s = a0 + a1;
                ehdot   = e0 + e1;
                s = dpp_add<DPP_QX1>(s);               // == += shfl_xor 1
                ehdot = dpp_add<DPP_QX1>(ehdot);
                float qh = fmaxf(aq + s, 0.f);
                float cq = (c1 == 0) ? qh * qpj : 0.f;
                // 64-lane sum via DPP tree (bitwise == old butterfly per
                // IEEE add commutativity; values group-uniform at each level)
                cq = dpp_add<DPP_QX1>(cq);
                cq = dpp_add<DPP_QX2>(cq);
                cq = dpp_add<DPP_RHM>(cq);
                cq = dpp_add<DPP_RM>(cq);
                cq = dpp_add<DPP_B15>(cq);
                cq = dpp_add<DPP_B31>(cq);
                float wsum = __builtin_bit_cast(float,
                    __builtin_amdgcn_readlane(__builtin_bit_cast(int, cq), 63));
                if ((tid & 63) == 0) red[tid >> 6] = wsum;
                __syncthreads();                           // B1
                float qlog = ((red[0] + red[1]) + (red[2] + red[3])) +
                             ((red[4] + red[5]) + (red[6] + red[7]));
                y_t = sigmoidf_(leu + qlog);
            } else {
                float e0 = 0.f, e1 = 0.f;
#pragma unroll
                for (int g = 0; g < 8; ++g) {
                    u32x4 hv = hh4[c1 * 8 + g];
                    DOT2(e0, hv[0], weh2_[g * 4 + 0]);
                    DOT2(e1, hv[1], weh2_[g * 4 + 1]);
                    DOT2(e0, hv[2], weh2_[g * 4 + 2]);
                    DOT2(e1, hv[3], weh2_[g * 4 + 3]);
                }
                ehdot = e0 + e1;
                ehdot = dpp_add<DPP_QX1>(ehdot);
                y_t = yin;
            }

            // S3 finalize: eh = relu(Ae + y*wey + h-dot); pack pairs
            {
                float eh = fmaxf(fmaf(y_t, wey, ae) + ehdot, 0.f);
                float epart = dpp_mov<DPP_QX2>(eh);        // lane^2 exact
                if ((tid & 3) == 0) eh2[j >> 1] = packf16(eh, epart);
            }
            __syncthreads();                               // B3

            // S4: em/es over eh(256); z = ez*softplus(es)+em
            {
                const u32x4* __restrict__ eb4 = (const u32x4*)eh2;
                float b0 = 0.f, b1 = 0.f;
#pragma unroll
                for (int g = 0; g < 8; ++g) {
                    u32x4 ev = eb4[c4 * 8 + g];
                    u32x4 wv = wm2[g][tid];
                    DOT2(b0, ev[0], wv[0]); DOT2(b1, ev[1], wv[1]);
                    DOT2(b0, ev[2], wv[2]); DOT2(b1, ev[3], wv[3]);
                }
                float s = b0 + b1;
                s = dpp_add<DPP_QX1>(s);
                s = dpp_add<DPP_QX2>(s);
                float other = dpp_mov<DPP_RHM>(s);         // xor4 on quad-uniform
                float em_pre = k4s ? other : s;
                float es_pre = k4s ? s : other;
                float es = softplusf_(es_pre);
                float zm = fmaf(ezv, es, em_pre);
                float zpart = dpp_mov<DPP_RM>(zm);         // xor8 on 8-uniform
                if ((tid & 7) == 0) {
                    t_z[tt][m4] = zm; t_em[tt][m4] = em_pre; t_es[tt][m4] = es;
                }
                if ((tid & 15) == 0) z2[m4 >> 1] = packf16(zm, zpart);
            }
            __syncthreads();                               // B4

            // S5: h' = tanh(Ah + y*wihy + z@Wih_z + h@W_hh); pack pairs
            {
                const u32x4* __restrict__ zb4 = (const u32x4*)z2;
                float g0 = 0.f, g1 = 0.f;
#pragma unroll
                for (int g = 0; g < 2; ++g) {
                    u32x4 zv = zb4[c5 * 2 + g];
                    DOT2(g0, zv[0], wz2_[g * 4 + 0]);
                    DOT2(g1, zv[1], wz2_[g * 4 + 1]);
                    DOT2(g0, zv[2], wz2_[g * 4 + 2]);
                    DOT2(g1, zv[3], wz2_[g * 4 + 3]);
                }
#pragma unroll
                for (int g = 0; g < 4; ++g) {
                    u32x4 hv = hh4[c5 * 4 + g];
                    DOT2(g0, hv[0], wh2_[g * 4 + 0]);
                    DOT2(g1, hv[1], wh2_[g * 4 + 1]);
                    DOT2(g0, hv[2], wh2_[g * 4 + 2]);
                    DOT2(g1, hv[3], wh2_[g * 4 + 3]);
                }
                float s = g0 + g1;
                s = dpp_add<DPP_QX1>(s);
                s = dpp_add<DPP_QX2>(s);
                float hn = tanh_fast(fmaf(y_t, wihy, ahv) + s);
                float hpart = dpp_mov<DPP_RHM>(hn);        // xor4 on quad-uniform
                if (c5 == 0) t_h[tt][o5] = hn;
                if ((tid & 7) == 0) hh2[nxt][o5 >> 1] = packf16(hn, hpart);
                if (tid == 0) t_y[tt] = y_t;
            }
            __syncthreads();                               // B5
        }

        flushb(t0);            // trajectory for this batch
        write_regs();          // s_* for next batch (loads long in flight)
        __syncthreads();       // batch barrier
    }
}

// ---------------------------------------------------------------------------
// Post-pass: one block per timestep (unchanged, full f32).
// ---------------------------------------------------------------------------
__global__ __launch_bounds__(256) void k_post(
    const float* __restrict__ x, const float* __restrict__ yin_g,
    const float* __restrict__ Wpz, const float* __restrict__ Wpzm,
    const float* __restrict__ Wpzs,
    const float* __restrict__ Wpy, const float* __restrict__ ppr,
    const float* __restrict__ Wqy, const float* __restrict__ qpr,
    const float* __restrict__ Wd, const float* __restrict__ Wdm,
    const float* __restrict__ Wds,
    const float* __restrict__ Aq,
    const float* __restrict__ h_st, const float* __restrict__ z_st,
    const float* __restrict__ em_st, const float* __restrict__ es_st,
    const float* __restrict__ y_st,
    float* __restrict__ part)
{
    const float CC = -0.9189385332046727f;  // -0.5*log(2*pi)
    const int t = blockIdx.x;
    const int tid = threadIdx.x;
    __shared__ float xp[128], xdv[128], xcv[128], hp[128];
    __shared__ float zp[64], ztv[64], emv[64], esv[64];
    __shared__ float pzh[256], dhv[256];
    __shared__ float pmv[64], psv[64], dmv[128], dsv[128];
    __shared__ float rl[16];

    const int tp = t ? (t - 1) : (T - 1);
    if (tid < 128) {
        xp[tid]  = x[(size_t)tp * 128 + tid];
        xdv[tid] = t ? x[(size_t)(t - 1) * 128 + tid] : 0.f;
        xcv[tid] = x[(size_t)t * 128 + tid];
        hp[tid]  = t ? h_st[(size_t)(t - 1) * 128 + tid] : 0.f;
    } else {
        int m = tid - 128;
        if (m < 64) {
            zp[m]  = t ? z_st[(size_t)(t - 1) * 64 + m] : 0.f;
            ztv[m] = z_st[(size_t)t * 64 + m];
        } else {
            m -= 64;
            emv[m] = em_st[(size_t)t * 64 + m];
            esv[m] = es_st[(size_t)t * 64 + m];
        }
    }
    __syncthreads();

    const float y_t = y_st[t];
    const float y_prev = t ? y_st[t - 1] : 0.f;
    const float lf = (yin_g[t] != -1.0f) ? 1.f : 0.f;
    const int jj = tid;

    float ap = 0.f;
#pragma unroll 4
    for (int i = 0; i < 128; ++i) ap = fmaf(xp[i], Wpy[i * 256 + jj], ap);
    ap = fmaf(y_prev, Wpy[128 * 256 + jj], ap);
    float cp = fmaxf(ap, 0.f) * ppr[jj];

    float aqv = Aq[(size_t)t * 256 + jj];
#pragma unroll 4
    for (int i = 0; i < 128; ++i) aqv = fmaf(hp[i], Wqy[(128 + i) * 256 + jj], aqv);
    float cq = fmaxf(aqv, 0.f) * qpr[jj];

    float az = 0.f;
#pragma unroll 4
    for (int m = 0; m < 64; ++m) az = fmaf(zp[m], Wpz[m * 256 + jj], az);
    pzh[jj] = fmaxf(az, 0.f);

    float ad = 0.f;
#pragma unroll 4
    for (int i = 0; i < 128; ++i) ad = fmaf(xdv[i], Wd[i * 256 + jj], ad);
#pragma unroll 4
    for (int m = 0; m < 64; ++m) ad = fmaf(ztv[m], Wd[(128 + m) * 256 + jj], ad);
    ad = fmaf(y_t, Wd[192 * 256 + jj], ad);
    dhv[jj] = fmaxf(ad, 0.f);
    __syncthreads();

    {
        const int i_ = tid & 127;
        const float* W = (tid < 128) ? Wdm : Wds;
        float a = 0.f;
#pragma unroll 4
        for (int q2 = 0; q2 < 256; ++q2) a = fmaf(dhv[q2], W[q2 * 128 + i_], a);
        if (tid < 128) dmv[i_] = a; else dsv[i_] = softplusf_(a);
    }
    if (tid < 128) {
        const int m = tid & 63;
        const float* W = (tid < 64) ? Wpzm : Wpzs;
        float a = 0.f;
#pragma unroll 4
        for (int q2 = 0; q2 < 256; ++q2) a = fmaf(pzh[q2], W[q2 * 64 + m], a);
        if (tid < 64) pmv[m] = a; else psv[m] = softplusf_(a);
    }
    __syncthreads();

    float kldc = 0.f, recc = 0.f;
    if (tid < 64) {
        float es = esv[tid], em = emv[tid], pm = pmv[tid], ps = psv[tid];
        float d = em - pm;
        kldc = __logf(ps / es) + (es * es + d * d) / (2.f * ps * ps) - 0.5f;
    }
    if (tid < 128) {
        float dm = dmv[tid], ds = dsv[tid], xv = xcv[tid];
        float d = xv - dm;
        recc = CC + __logf(ds) + d * d / (2.f * ds * ds);
    }

#pragma unroll
    for (int d = 1; d < 64; d <<= 1) {
        cp += __shfl_xor(cp, d);
        cq += __shfl_xor(cq, d);
        kldc += __shfl_xor(kldc, d);
        recc += __shfl_xor(recc, d);
    }
    if ((tid & 63) == 0) {
        const int w = tid >> 6;
        rl[w * 4 + 0] = cp; rl[w * 4 + 1] = cq;
        rl[w * 4 + 2] = kldc; rl[w * 4 + 3] = recc;
    }
    __syncthreads();
    if (tid == 0) {
        float plog = rl[0] + rl[4] + rl[8]  + rl[12];
        float qlog = rl[1] + rl[5] + rl[9]  + rl[13];
        float kld  = rl[2] + rl[6] + rl[10] + rl[14];
        float rec  = rl[3] + rl[7] + rl[11] + rl[15];
        float p = sigmoidf_(plog), q = sigmoidf_(qlog);
        float bce  = -(y_t * __logf(p) + (1.f - y_t) * __logf(1.f - p));
        float addt = y_t * __logf(p * q) + (1.f - y_t) * __logf((1.f - p) * (1.f - q));
        float kcat = p * __logf(p / q) + (1.f - p) * __logf((1.f - p) / (1.f - q));
        float ul = 1.f - lf;
        float* pr = part + (size_t)t * 7;
        pr[0] = lf * kld;  pr[1] = lf * rec;  pr[2] = lf * bce;
        pr[3] = ul * kld;  pr[4] = ul * rec;  pr[5] = ul * kcat;
        pr[6] = lf * addt;
    }
}

__global__ __launch_bounds__(256) void k_final(const float* __restrict__ part,
                                               float* __restrict__ out)
{
    const int o = blockIdx.x;
    float s = 0.f;
    for (int b = threadIdx.x; b < T; b += 256) s += part[(size_t)b * 7 + o];
#pragma unroll
    for (int d = 1; d < 64; d <<= 1) s += __shfl_xor(s, d);
    __shared__ float l[4];
    if ((threadIdx.x & 63) == 0) l[threadIdx.x >> 6] = s;
    __syncthreads();
    if (threadIdx.x == 0) out[o] = (l[0] + l[1]) + (l[2] + l[3]);
}

extern "C" void kernel_launch(void* const* d_in, const int* in_sizes, int n_in,
                              void* d_out, int out_size, void* d_ws, size_t ws_size,
                              hipStream_t stream) {
    (void)in_sizes; (void)n_in; (void)out_size; (void)ws_size;
    const float* x    = (const float*)d_in[0];
    const float* yin  = (const float*)d_in[1];
    const float* ez   = (const float*)d_in[2];
    const float* eu   = (const float*)d_in[3];
    const float* Wpz  = (const float*)d_in[4];
    const float* Wpzm = (const float*)d_in[5];
    const float* Wpzs = (const float*)d_in[6];
    const float* Wpy  = (const float*)d_in[7];
    const float* ppr  = (const float*)d_in[8];
    const float* Wqy  = (const float*)d_in[9];
    const float* qpr  = (const float*)d_in[10];
    const float* Wenc = (const float*)d_in[11];
    const float* Wem  = (const float*)d_in[12];
    const float* Wes  = (const float*)d_in[13];
    const float* Wd   = (const float*)d_in[14];
    const float* Wdm  = (const float*)d_in[15];
    const float* Wds  = (const float*)d_in[16];
    const float* Wih  = (const float*)d_in[17];
    const float* Whh  = (const float*)d_in[18];

    float* ws = (float*)d_ws;
    float* Aq    = ws;                           // T*256
    float* Ae    = Aq    + (size_t)T * 256;      // T*256
    float* Ah    = Ae    + (size_t)T * 256;      // T*128
    float* h_st  = Ah    + (size_t)T * 128;      // T*128
    float* z_st  = h_st  + (size_t)T * 128;      // T*64
    float* em_st = z_st  + (size_t)T * 64;       // T*64
    float* es_st = em_st + (size_t)T * 64;       // T*64
    float* y_st  = es_st + (size_t)T * 64;       // T
    float* part  = y_st  + (size_t)T;            // T*7
    float* leu   = part  + (size_t)T * 7;        // T

    k_pre<<<T / 16, 256, 0, stream>>>(x, eu, Wqy, Wenc, Wih, Aq, Ae, Ah, leu);
    k_scan<<<1, 512, 0, stream>>>(Wqy, qpr, Wenc, Wem, Wes, Wih, Whh,
                                  yin, leu, ez, Aq, Ae, Ah,
                                  h_st, z_st, em_st, es_st, y_st);
    k_post<<<T, 256, 0, stream>>>(x, yin, Wpz, Wpzm, Wpzs, Wpy, ppr, Wqy, qpr,
                                  Wd, Wdm, Wds, Aq, h_st, z_st, em_st, es_st,
                                  y_st, part);
    k_final<<<7, 256, 0, stream>>>(part, (float*)d_out);
}

// Round 15
// 25274.373 us; speedup vs baseline: 1.2277x; 1.0272x over previous
//
#include <hip/hip_runtime.h>
#include <math.h>

#define T 16384

typedef float f32x4 __attribute__((ext_vector_type(4)));
typedef unsigned int u32x4 __attribute__((ext_vector_type(4)));
typedef _Float16 h16x2 __attribute__((ext_vector_type(2)));

__device__ __forceinline__ float softplusf_(float x) {
    return (x > 15.f) ? x : __logf(1.f + __expf(x));
}
__device__ __forceinline__ float sigmoidf_(float x) {
    return 1.f / (1.f + __expf(-x));
}
__device__ __forceinline__ float tanh_fast(float x) {
    float xc = fminf(fmaxf(x, -15.f), 15.f);
    float e = __expf(2.f * xc);
    return (e - 1.f) / (e + 1.f);
}
__device__ __forceinline__ unsigned packf16(float a, float b) {
    h16x2 p; p[0] = (_Float16)a; p[1] = (_Float16)b;   // RTN converts
    return __builtin_bit_cast(unsigned, p);
}
#define H2(u) __builtin_bit_cast(h16x2, (unsigned)(u))
// f32 += f16*f16 + f16*f16 (V_DOT2_F32_F16)
#define DOT2(ACC, UH, UW) ACC = __builtin_amdgcn_fdot2(H2(UH), H2(UW), ACC, false)

// ---- DPP cross-lane (VALU pipe) ----
#define DPP_QX1 0xB1   // quad_perm(1,0,3,2)  == xor 1
#define DPP_QX2 0x4E   // quad_perm(2,3,0,1)  == xor 2
#define DPP_RHM 0x141  // row_half_mirror == xor 4 on quad-uniform
#define DPP_RM  0x140  // row_mirror == xor 8 on 8-uniform
#define DPP_B15 0x142  // row_bcast15
#define DPP_B31 0x143  // row_bcast31
template <int CTRL>
__device__ __forceinline__ float dpp_mov(float s) {
    return __builtin_bit_cast(float,
        __builtin_amdgcn_update_dpp(0, __builtin_bit_cast(int, s), CTRL, 0xf, 0xf, true));
}
template <int CTRL>
__device__ __forceinline__ float dpp_add(float s) {
    return s + dpp_mov<CTRL>(s);
}

// ---------------------------------------------------------------------------
// Precompute x-dependent matvec parts + logit(eps_u) (fully parallel, f32).
// ---------------------------------------------------------------------------
__global__ __launch_bounds__(256) void k_pre(
    const float* __restrict__ x, const float* __restrict__ eu_g,
    const float* __restrict__ Wqy, const float* __restrict__ Wenc,
    const float* __restrict__ Wih,
    float* __restrict__ Aq, float* __restrict__ Ae, float* __restrict__ Ah,
    float* __restrict__ leu_g)
{
    __shared__ float xs[16 * 128];
    const int t0 = blockIdx.x * 16;
    for (int r = threadIdx.x; r < 16 * 128; r += 256) xs[r] = x[t0 * 128 + r];
    __syncthreads();
    const int j = threadIdx.x;
    if (j < 16) {
        float eu = eu_g[t0 + j];
        leu_g[t0 + j] = __logf(eu) - __logf(1.f - eu);
    }
    for (int tt = 0; tt < 16; ++tt) {
        float aq = 0.f, ae = 0.f;
#pragma unroll 8
        for (int i = 0; i < 128; ++i) {
            float xv = xs[tt * 128 + i];
            aq = fmaf(xv, Wqy[i * 256 + j], aq);
            ae = fmaf(xv, Wenc[i * 256 + j], ae);
        }
        Aq[(size_t)(t0 + tt) * 256 + j] = aq;
        Ae[(size_t)(t0 + tt) * 256 + j] = ae;
    }
    if (j < 128) {
        for (int tt = 0; tt < 16; ++tt) {
            float ah = 0.f;
#pragma unroll 8
            for (int i = 0; i < 128; ++i)
                ah = fmaf(xs[tt * 128 + i], Wih[(65 + i) * 128 + j], ah);
            Ah[(size_t)(t0 + tt) * 128 + j] = ah;
        }
    }
}

// ---------------------------------------------------------------------------
// Sequential scan: 1 block x 512 threads, f16 weights (r11 placement), DPP
// cross-lane (r14). NEW: S5's h-dot hoisted into the S3 phase (depends only
// on h and y_t) so the post-B4 spine is just the short z-dot + tanh.
// ---------------------------------------------------------------------------
__global__
__attribute__((amdgpu_flat_work_group_size(512, 512)))
__attribute__((amdgpu_waves_per_eu(2, 2)))
void k_scan(
    const float* __restrict__ Wqy, const float* __restrict__ qpr,
    const float* __restrict__ Wenc,
    const float* __restrict__ Wem0, const float* __restrict__ Wes0,
    const float* __restrict__ Wih, const float* __restrict__ Whh,
    const float* __restrict__ yin_g, const float* __restrict__ leu_g,
    const float* __restrict__ ez_g,
    const float* __restrict__ Aq, const float* __restrict__ Ae,
    const float* __restrict__ Ah,
    float* __restrict__ h_st, float* __restrict__ z_st,
    float* __restrict__ em_st, float* __restrict__ es_st,
    float* __restrict__ y_st)
{
    const int tid = threadIdx.x;
    const int j   = tid >> 1, c1 = tid & 1;                          // S1/S3
    const int m4  = tid >> 3; const int k4s = (tid >> 2) & 1; const int c4 = tid & 3; // S4
    const int o5  = tid >> 2, c5 = tid & 3;                          // S5

    // ---- LDS (~145 KB) ----
    __shared__ __align__(16) u32x4 wq2[8][512];      // 64 KB W_q_y h-part (f16)
    __shared__ __align__(16) u32x4 wm2[8][512];      // 64 KB W_em/es (f16)
    __shared__ __align__(16) float s_aq[4][256];
    __shared__ __align__(16) float s_ae[4][256];
    __shared__ __align__(16) float s_ah[4][128];
    __shared__ __align__(16) float s_ez[4][64];
    __shared__ __align__(16) float s_yin[4];
    __shared__ __align__(16) float s_leu[4];
    __shared__ __align__(16) float t_h[4][128];
    __shared__ __align__(16) float t_z[4][64];
    __shared__ __align__(16) float t_em[4][64];
    __shared__ __align__(16) float t_es[4][64];
    __shared__ float t_y[4];
    __shared__ __align__(16) unsigned hh2[2][64];    // h packed (f16 pairs)
    __shared__ __align__(16) unsigned eh2[128];      // eh packed
    __shared__ __align__(16) unsigned z2[32];        // z packed
    __shared__ float red[8];

    // ---- register weights (f16-packed u32, constant indices) ----
    unsigned weh2_[32];                              // W_enc-h chunk (64 f)
#pragma unroll
    for (int g = 0; g < 8; ++g)
#pragma unroll
        for (int e = 0; e < 4; ++e) {
            const int k = g * 8 + 2 * e;
            weh2_[g * 4 + e] = packf16(Wenc[(129 + c1 * 64 + k) * 256 + j],
                                       Wenc[(129 + c1 * 64 + k + 1) * 256 + j]);
        }
    unsigned wh2_[16];                               // W_hh chunk (32 f)
#pragma unroll
    for (int g = 0; g < 4; ++g)
#pragma unroll
        for (int e = 0; e < 4; ++e) {
            const int k = g * 8 + 2 * e;
            wh2_[g * 4 + e] = packf16(Whh[(c5 * 32 + k) * 128 + o5],
                                      Whh[(c5 * 32 + k + 1) * 128 + o5]);
        }
    unsigned wz2_[8];                                // W_ih-z chunk (16 f)
#pragma unroll
    for (int p = 0; p < 8; ++p)
        wz2_[p] = packf16(Wih[(1 + c5 * 16 + 2 * p) * 128 + o5],
                          Wih[(1 + c5 * 16 + 2 * p + 1) * 128 + o5]);
    const float wey  = Wenc[128 * 256 + j];
    const float qpj  = qpr[j];
    const float wihy = Wih[o5];

    // ---- LDS weights: W_q_y h-part + W_em/es, thread-major ----
    for (int g = 0; g < 8; ++g) {
        u32x4 v;
#pragma unroll
        for (int e = 0; e < 4; ++e) {
            const int k = g * 8 + 2 * e;
            v[e] = packf16(Wqy[(128 + c1 * 64 + k) * 256 + j],
                           Wqy[(128 + c1 * 64 + k + 1) * 256 + j]);
        }
        wq2[g][tid] = v;
    }
    {
        const float* Wm = k4s ? Wes0 : Wem0;
        for (int g = 0; g < 8; ++g) {
            u32x4 v;
#pragma unroll
            for (int e = 0; e < 4; ++e) {
                const int k = g * 8 + 2 * e;
                v[e] = packf16(Wm[(c4 * 64 + k) * 64 + m4],
                               Wm[(c4 * 64 + k + 1) * 64 + m4]);
            }
            wm2[g][tid] = v;
        }
    }
    if (tid < 64) hh2[0][tid] = 0u;                  // h(0) = 0

    // ---- staging: global -> regs (early) -> LDS (late) ----
    f32x4 pA, pC;
    auto load_regs = [&](int t0) {
        if (tid < 256) pA = ((const f32x4*)(Aq + (size_t)t0 * 256))[tid];
        else           pA = ((const f32x4*)(Ae + (size_t)t0 * 256))[tid - 256];
        if (tid < 128)       pC = ((const f32x4*)(Ah + (size_t)t0 * 128))[tid];
        else if (tid < 192)  pC = ((const f32x4*)(ez_g + (size_t)t0 * 64))[tid - 128];
        else if (tid == 192) pC = *(const f32x4*)(yin_g + t0);
        else if (tid == 193) pC = *(const f32x4*)(leu_g + t0);
    };
    auto write_regs = [&]() {
        if (tid < 256) ((f32x4*)&s_aq[0][0])[tid] = pA;
        else           ((f32x4*)&s_ae[0][0])[tid - 256] = pA;
        if (tid < 128)       ((f32x4*)&s_ah[0][0])[tid] = pC;
        else if (tid < 192)  ((f32x4*)&s_ez[0][0])[tid - 128] = pC;
        else if (tid == 192) *(f32x4*)s_yin = pC;
        else if (tid == 193) *(f32x4*)s_leu = pC;
    };
    auto flushb = [&](int t0) {
        if (tid < 128) {
            ((f32x4*)(h_st + (size_t)t0 * 128))[tid] = ((const f32x4*)&t_h[0][0])[tid];
        } else if (tid < 192) {
            ((f32x4*)(z_st + (size_t)t0 * 64))[tid - 128] = ((const f32x4*)&t_z[0][0])[tid - 128];
        } else if (tid < 256) {
            ((f32x4*)(em_st + (size_t)t0 * 64))[tid - 192] = ((const f32x4*)&t_em[0][0])[tid - 192];
        } else if (tid < 320) {
            ((f32x4*)(es_st + (size_t)t0 * 64))[tid - 256] = ((const f32x4*)&t_es[0][0])[tid - 256];
        } else if (tid < 324) {
            y_st[t0 + (tid - 320)] = t_y[tid - 320];
        }
    };

    load_regs(0);
    write_regs();
    __syncthreads();

    for (int t0 = 0; t0 < T; t0 += 4) {
        const int tnb = (t0 + 4 < T) ? t0 + 4 : t0;
        load_regs(tnb);                                    // issue early (T14)

        for (int tt = 0; tt < 4; ++tt) {
            const int t = t0 + tt;
            const int cur = t & 1, nxt = cur ^ 1;
            const float aq  = s_aq[tt][j];
            const float ae  = s_ae[tt][j];
            const float yin = s_yin[tt];
            const float leu = s_leu[tt];
            const float ezv = s_ez[tt][m4];
            const float ahv = s_ah[tt][o5];
            const u32x4* __restrict__ hh4 = (const u32x4*)&hh2[cur][0];

            float y_t, ehdot;
            if (yin == -1.0f) {
                // fused q-dot (LDS f16) + eh-dot (reg f16), shared h pairs
                float a0 = 0.f, a1 = 0.f, e0 = 0.f, e1 = 0.f;
#pragma unroll
                for (int g = 0; g < 8; ++g) {
                    u32x4 hv = hh4[c1 * 8 + g];
                    u32x4 qv = wq2[g][tid];
                    DOT2(a0, hv[0], qv[0]); DOT2(a1, hv[1], qv[1]);
                    DOT2(a0, hv[2], qv[2]); DOT2(a1, hv[3], qv[3]);
                    DOT2(e0, hv[0], weh2_[g * 4 + 0]);
                    DOT2(e1, hv[1], weh2_[g * 4 + 1]);
                    DOT2(e0, hv[2], weh2_[g * 4 + 2]);
                    DOT2(e1, hv[3], weh2_[g * 4 + 3]);
                }
                float s = a0 + a1;
                ehdot   = e0 + e1;
                s = dpp_add<DPP_QX1>(s);
                ehdot = dpp_add<DPP_QX1>(ehdot);
                float qh = fmaxf(aq + s, 0.f);
                float cq = (c1 == 0) ? qh * qpj : 0.f;
                cq = dpp_add<DPP_QX1>(cq);
                cq = dpp_add<DPP_QX2>(cq);
                cq = dpp_add<DPP_RHM>(cq);
                cq = dpp_add<DPP_RM>(cq);
                cq = dpp_add<DPP_B15>(cq);
                cq = dpp_add<DPP_B31>(cq);
                float wsum = __builtin_bit_cast(float,
                    __builtin_amdgcn_readlane(__builtin_bit_cast(int, cq), 63));
                if ((tid & 63) == 0) red[tid >> 6] = wsum;
                __syncthreads();                           // B1
                float qlog = ((red[0] + red[1]) + (red[2] + red[3])) +
                             ((red[4] + red[5]) + (red[6] + red[7]));
                y_t = sigmoidf_(leu + qlog);
            } else {
                float e0 = 0.f, e1 = 0.f;
#pragma unroll
                for (int g = 0; g < 8; ++g) {
                    u32x4 hv = hh4[c1 * 8 + g];
                    DOT2(e0, hv[0], weh2_[g * 4 + 0]);
                    DOT2(e1, hv[1], weh2_[g * 4 + 1]);
                    DOT2(e0, hv[2], weh2_[g * 4 + 2]);
                    DOT2(e1, hv[3], weh2_[g * 4 + 3]);
                }
                ehdot = e0 + e1;
                ehdot = dpp_add<DPP_QX1>(ehdot);
                y_t = yin;
            }

            // S3 finalize: eh = relu(Ae + y*wey + h-dot); pack pairs.
            // HOISTED: S5's h-dot (only needs h) runs here, off the spine.
            float gh0 = 0.f, gh1 = 0.f;
            {
                float eh = fmaxf(fmaf(y_t, wey, ae) + ehdot, 0.f);
                float epart = dpp_mov<DPP_QX2>(eh);        // lane^2 exact
                if ((tid & 3) == 0) eh2[j >> 1] = packf16(eh, epart);
#pragma unroll
                for (int g = 0; g < 4; ++g) {
                    u32x4 hv = hh4[c5 * 4 + g];
                    DOT2(gh0, hv[0], wh2_[g * 4 + 0]);
                    DOT2(gh1, hv[1], wh2_[g * 4 + 1]);
                    DOT2(gh0, hv[2], wh2_[g * 4 + 2]);
                    DOT2(gh1, hv[3], wh2_[g * 4 + 3]);
                }
            }
            __syncthreads();                               // B3

            // S4: em/es over eh(256); z = ez*softplus(es)+em
            {
                const u32x4* __restrict__ eb4 = (const u32x4*)eh2;
                float b0 = 0.f, b1 = 0.f;
#pragma unroll
                for (int g = 0; g < 8; ++g) {
                    u32x4 ev = eb4[c4 * 8 + g];
                    u32x4 wv = wm2[g][tid];
                    DOT2(b0, ev[0], wv[0]); DOT2(b1, ev[1], wv[1]);
                    DOT2(b0, ev[2], wv[2]); DOT2(b1, ev[3], wv[3]);
                }
                float s = b0 + b1;
                s = dpp_add<DPP_QX1>(s);
                s = dpp_add<DPP_QX2>(s);
                float other = dpp_mov<DPP_RHM>(s);         // xor4 on quad-uniform
                float em_pre = k4s ? other : s;
                float es_pre = k4s ? s : other;
                float es = softplusf_(es_pre);
                float zm = fmaf(ezv, es, em_pre);
                float zpart = dpp_mov<DPP_RM>(zm);         // xor8 on 8-uniform
                if ((tid & 7) == 0) {
                    t_z[tt][m4] = zm; t_em[tt][m4] = em_pre; t_es[tt][m4] = es;
                }
                if ((tid & 15) == 0) z2[m4 >> 1] = packf16(zm, zpart);
            }
            __syncthreads();                               // B4

            // S5: h' = tanh(Ah + y*wihy + z@Wih_z + gh); only z-dot remains
            {
                const u32x4* __restrict__ zb4 = (const u32x4*)z2;
                float g0 = 0.f, g1 = 0.f;
#pragma unroll
                for (int g = 0; g < 2; ++g) {
                    u32x4 zv = zb4[c5 * 2 + g];
                    DOT2(g0, zv[0], wz2_[g * 4 + 0]);
                    DOT2(g1, zv[1], wz2_[g * 4 + 1]);
                    DOT2(g0, zv[2], wz2_[g * 4 + 2]);
                    DOT2(g1, zv[3], wz2_[g * 4 + 3]);
                }
                float s = (g0 + g1) + (gh0 + gh1);
                s = dpp_add<DPP_QX1>(s);
                s = dpp_add<DPP_QX2>(s);
                float hn = tanh_fast(fmaf(y_t, wihy, ahv) + s);
                float hpart = dpp_mov<DPP_RHM>(hn);        // xor4 on quad-uniform
                if (c5 == 0) t_h[tt][o5] = hn;
                if ((tid & 7) == 0) hh2[nxt][o5 >> 1] = packf16(hn, hpart);
                if (tid == 0) t_y[tt] = y_t;
            }
            __syncthreads();                               // B5
        }

        flushb(t0);            // trajectory for this batch
        write_regs();          // s_* for next batch (loads long in flight)
        __syncthreads();       // batch barrier
    }
}

// ---------------------------------------------------------------------------
// Post-pass: one block per timestep (unchanged, full f32).
// ---------------------------------------------------------------------------
__global__ __launch_bounds__(256) void k_post(
    const float* __restrict__ x, const float* __restrict__ yin_g,
    const float* __restrict__ Wpz, const float* __restrict__ Wpzm,
    const float* __restrict__ Wpzs,
    const float* __restrict__ Wpy, const float* __restrict__ ppr,
    const float* __restrict__ Wqy, const float* __restrict__ qpr,
    const float* __restrict__ Wd, const float* __restrict__ Wdm,
    const float* __restrict__ Wds,
    const float* __restrict__ Aq,
    const float* __restrict__ h_st, const float* __restrict__ z_st,
    const float* __restrict__ em_st, const float* __restrict__ es_st,
    const float* __restrict__ y_st,
    float* __restrict__ part)
{
    const float CC = -0.9189385332046727f;  // -0.5*log(2*pi)
    const int t = blockIdx.x;
    const int tid = threadIdx.x;
    __shared__ float xp[128], xdv[128], xcv[128], hp[128];
    __shared__ float zp[64], ztv[64], emv[64], esv[64];
    __shared__ float pzh[256], dhv[256];
    __shared__ float pmv[64], psv[64], dmv[128], dsv[128];
    __shared__ float rl[16];

    const int tp = t ? (t - 1) : (T - 1);
    if (tid < 128) {
        xp[tid]  = x[(size_t)tp * 128 + tid];
        xdv[tid] = t ? x[(size_t)(t - 1) * 128 + tid] : 0.f;
        xcv[tid] = x[(size_t)t * 128 + tid];
        hp[tid]  = t ? h_st[(size_t)(t - 1) * 128 + tid] : 0.f;
    } else {
        int m = tid - 128;
        if (m < 64) {
            zp[m]  = t ? z_st[(size_t)(t - 1) * 64 + m] : 0.f;
            ztv[m] = z_st[(size_t)t * 64 + m];
        } else {
            m -= 64;
            emv[m] = em_st[(size_t)t * 64 + m];
            esv[m] = es_st[(size_t)t * 64 + m];
        }
    }
    __syncthreads();

    const float y_t = y_st[t];
    const float y_prev = t ? y_st[t - 1] : 0.f;
    const float lf = (yin_g[t] != -1.0f) ? 1.f : 0.f;
    const int jj = tid;

    float ap = 0.f;
#pragma unroll 4
    for (int i = 0; i < 128; ++i) ap = fmaf(xp[i], Wpy[i * 256 + jj], ap);
    ap = fmaf(y_prev, Wpy[128 * 256 + jj], ap);
    float cp = fmaxf(ap, 0.f) * ppr[jj];

    float aqv = Aq[(size_t)t * 256 + jj];
#pragma unroll 4
    for (int i = 0; i < 128; ++i) aqv = fmaf(hp[i], Wqy[(128 + i) * 256 + jj], aqv);
    float cq = fmaxf(aqv, 0.f) * qpr[jj];

    float az = 0.f;
#pragma unroll 4
    for (int m = 0; m < 64; ++m) az = fmaf(zp[m], Wpz[m * 256 + jj], az);
    pzh[jj] = fmaxf(az, 0.f);

    float ad = 0.f;
#pragma unroll 4
    for (int i = 0; i < 128; ++i) ad = fmaf(xdv[i], Wd[i * 256 + jj], ad);
#pragma unroll 4
    for (int m = 0; m < 64; ++m) ad = fmaf(ztv[m], Wd[(128 + m) * 256 + jj], ad);
    ad = fmaf(y_t, Wd[192 * 256 + jj], ad);
    dhv[jj] = fmaxf(ad, 0.f);
    __syncthreads();

    {
        const int i_ = tid & 127;
        const float* W = (tid < 128) ? Wdm : Wds;
        float a = 0.f;
#pragma unroll 4
        for (int q2 = 0; q2 < 256; ++q2) a = fmaf(dhv[q2], W[q2 * 128 + i_], a);
        if (tid < 128) dmv[i_] = a; else dsv[i_] = softplusf_(a);
    }
    if (tid < 128) {
        const int m = tid & 63;
        const float* W = (tid < 64) ? Wpzm : Wpzs;
        float a = 0.f;
#pragma unroll 4
        for (int q2 = 0; q2 < 256; ++q2) a = fmaf(pzh[q2], W[q2 * 64 + m], a);
        if (tid < 64) pmv[m] = a; else psv[m] = softplusf_(a);
    }
    __syncthreads();

    float kldc = 0.f, recc = 0.f;
    if (tid < 64) {
        float es = esv[tid], em = emv[tid], pm = pmv[tid], ps = psv[tid];
        float d = em - pm;
        kldc = __logf(ps / es) + (es * es + d * d) / (2.f * ps * ps) - 0.5f;
    }
    if (tid < 128) {
        float dm = dmv[tid], ds = dsv[tid], xv = xcv[tid];
        float d = xv - dm;
        recc = CC + __logf(ds) + d * d / (2.f * ds * ds);
    }

#pragma unroll
    for (int d = 1; d < 64; d <<= 1) {
        cp += __shfl_xor(cp, d);
        cq += __shfl_xor(cq, d);
        kldc += __shfl_xor(kldc, d);
        recc += __shfl_xor(recc, d);
    }
    if ((tid & 63) == 0) {
        const int w = tid >> 6;
        rl[w * 4 + 0] = cp; rl[w * 4 + 1] = cq;
        rl[w * 4 + 2] = kldc; rl[w * 4 + 3] = recc;
    }
    __syncthreads();
    if (tid == 0) {
        float plog = rl[0] + rl[4] + rl[8]  + rl[12];
        float qlog = rl[1] + rl[5] + rl[9]  + rl[13];
        float kld  = rl[2] + rl[6] + rl[10] + rl[14];
        float rec  = rl[3] + rl[7] + rl[11] + rl[15];
        float p = sigmoidf_(plog), q = sigmoidf_(qlog);
        float bce  = -(y_t * __logf(p) + (1.f - y_t) * __logf(1.f - p));
        float addt = y_t * __logf(p * q) + (1.f - y_t) * __logf((1.f - p) * (1.f - q));
        float kcat = p * __logf(p / q) + (1.f - p) * __logf((1.f - p) / (1.f - q));
        float ul = 1.f - lf;
        float* pr = part + (size_t)t * 7;
        pr[0] = lf * kld;  pr[1] = lf * rec;  pr[2] = lf * bce;
        pr[3] = ul * kld;  pr[4] = ul * rec;  pr[5] = ul * kcat;
        pr[6] = lf * addt;
    }
}

__global__ __launch_bounds__(256) void k_final(const float* __restrict__ part,
                                               float* __restrict__ out)
{
    const int o = blockIdx.x;
    float s = 0.f;
    for (int b = threadIdx.x; b < T; b += 256) s += part[(size_t)b * 7 + o];
#pragma unroll
    for (int d = 1; d < 64; d <<= 1) s += __shfl_xor(s, d);
    __shared__ float l[4];
    if ((threadIdx.x & 63) == 0) l[threadIdx.x >> 6] = s;
    __syncthreads();
    if (threadIdx.x == 0) out[o] = (l[0] + l[1]) + (l[2] + l[3]);
}

extern "C" void kernel_launch(void* const* d_in, const int* in_sizes, int n_in,
                              void* d_out, int out_size, void* d_ws, size_t ws_size,
                              hipStream_t stream) {
    (void)in_sizes; (void)n_in; (void)out_size; (void)ws_size;
    const float* x    = (const float*)d_in[0];
    const float* yin  = (const float*)d_in[1];
    const float* ez   = (const float*)d_in[2];
    const float* eu   = (const float*)d_in[3];
    const float* Wpz  = (const float*)d_in[4];
    const float* Wpzm = (const float*)d_in[5];
    const float* Wpzs = (const float*)d_in[6];
    const float* Wpy  = (const float*)d_in[7];
    const float* ppr  = (const float*)d_in[8];
    const float* Wqy  = (const float*)d_in[9];
    const float* qpr  = (const float*)d_in[10];
    const float* Wenc = (const float*)d_in[11];
    const float* Wem  = (const float*)d_in[12];
    const float* Wes  = (const float*)d_in[13];
    const float* Wd   = (const float*)d_in[14];
    const float* Wdm  = (const float*)d_in[15];
    const float* Wds  = (const float*)d_in[16];
    const float* Wih  = (const float*)d_in[17];
    const float* Whh  = (const float*)d_in[18];

    float* ws = (float*)d_ws;
    float* Aq    = ws;                           // T*256
    float* Ae    = Aq    + (size_t)T * 256;      // T*256
    float* Ah    = Ae    + (size_t)T * 256;      // T*128
    float* h_st  = Ah    + (size_t)T * 128;      // T*128
    float* z_st  = h_st  + (size_t)T * 128;      // T*64
    float* em_st = z_st  + (size_t)T * 64;       // T*64
    float* es_st = em_st + (size_t)T * 64;       // T*64
    float* y_st  = es_st + (size_t)T * 64;       // T
    float* part  = y_st  + (size_t)T;            // T*7
    float* leu   = part  + (size_t)T * 7;        // T

    k_pre<<<T / 16, 256, 0, stream>>>(x, eu, Wqy, Wenc, Wih, Aq, Ae, Ah, leu);
    k_scan<<<1, 512, 0, stream>>>(Wqy, qpr, Wenc, Wem, Wes, Wih, Whh,
                                  yin, leu, ez, Aq, Ae, Ah,
                                  h_st, z_st, em_st, es_st, y_st);
    k_post<<<T, 256, 0, stream>>>(x, yin, Wpz, Wpzm, Wpzs, Wpy, ppr, Wqy, qpr,
                                  Wd, Wdm, Wds, Aq, h_st, z_st, em_st, es_st,
                                  y_st, part);
    k_final<<<7, 256, 0, stream>>>(part, (float*)d_out);
}